// Round 23
// baseline (115.937 us; speedup 1.0000x reference)
//
#include <hip/hip_runtime.h>
#include <hip/hip_bf16.h>
#include <math.h>

// Problem constants
#define PS    32768
#define DIN   1024
#define DMID  512
#define DATT  128
#define KMASK 16384
#define LKEEP 16384

typedef unsigned short u16;
typedef __attribute__((ext_vector_type(8))) short short8;
typedef __attribute__((ext_vector_type(4))) float f32x4;

__device__ __forceinline__ u16 f2bf(float f){
  unsigned x = __float_as_uint(f);
  unsigned r = (x + 0x7fffu + ((x >> 16) & 1u)) >> 16;  // RNE
  return (u16)r;
}
__device__ __forceinline__ u16 f2bf_hw(float f){
  __hip_bfloat16 h = __float2bfloat16(f);    // RNE; pairs fuse to v_cvt_pk_bf16_f32
  return *reinterpret_cast<u16*>(&h);
}
__device__ __forceinline__ float bf2f(u16 u){
  return __uint_as_float(((unsigned)u) << 16);
}
// monotonic key: larger float -> larger unsigned
__device__ __forceinline__ unsigned fkey(float f){
  unsigned b = __float_as_uint(f);
  return (b & 0x80000000u) ? ~b : (b | 0x80000000u);
}

#define GLDS16(g,l) __builtin_amdgcn_global_load_lds( \
    (const __attribute__((address_space(1))) void*)(g), \
    (__attribute__((address_space(3))) void*)(l), 16, 0, 0)

#define MEMPIN() asm volatile("" ::: "memory")

// ---------------------------------------------------------------------------
// Head kernel (R21-proven): blocks 0..31 = selection; blocks 32..175 = prep.
// ---------------------------------------------------------------------------
__global__ __launch_bounds__(1024) void k_head(const float* __restrict__ attn,
                                               int* __restrict__ keep_ids,
                                               const float* __restrict__ Wemb,
                                               u16* __restrict__ wet,
                                               const float* __restrict__ Wa1,
                                               u16* __restrict__ wa1t){
  __shared__ int histL[16384];
  __shared__ int suf[1024];
  __shared__ unsigned ck[4096];
  __shared__ int ci[4096];
  __shared__ float tile[4][32][33];
  __shared__ int sh_B, sh_kp, cnt;
  __shared__ unsigned sh_C;
  __shared__ int sh_thr;
  __shared__ int wbase[16];
  __shared__ int sh_base;
  const int t = threadIdx.x, b = blockIdx.x;

  if (b >= 32){
    const int grp = t >> 8, ts = t & 255;
    const int ob = (b - 32) * 4 + grp;
    const int tx = ts & 31, ty = ts >> 5;
    if (ob < 512){
      const int c0 = (ob & 15) * 32, r0 = (ob >> 4) * 32;   // Wemb [1024][512]
      for (int i = 0; i < 32; i += 8)
        tile[grp][ty + i][tx] = Wemb[(size_t)(r0 + ty + i) * DMID + c0 + tx];
      __syncthreads();
      for (int i = 0; i < 32; i += 8)
        wet[(size_t)(c0 + ty + i) * DIN + r0 + tx] = f2bf(tile[grp][tx][ty + i]);
    } else {
      const int b2 = ob - 512;                               // Wa1 [512][128]
      const int c0 = (b2 & 3) * 32, r0 = (b2 >> 2) * 32;
      for (int i = 0; i < 32; i += 8)
        tile[grp][ty + i][tx] = Wa1[(size_t)(r0 + ty + i) * DATT + c0 + tx];
      __syncthreads();
      for (int i = 0; i < 32; i += 8)
        wa1t[(size_t)(c0 + ty + i) * DMID + r0 + tx] = f2bf(tile[grp][tx][ty + i]);
    }
    return;
  }

  // selection (R19-proven)
  for (int i = t; i < 16384; i += 1024) histL[i] = 0;
  __syncthreads();
  for (int i = t; i < PS; i += 1024)
    atomicAdd(&histL[fkey(attn[i]) >> 18], 1);
  __syncthreads();

  int local[16]; int s = 0;
  const int base = t * 16;
  for (int j = 0; j < 16; j++){ local[j] = histL[base + j]; s += local[j]; }
  suf[t] = s; __syncthreads();
  for (int off = 1; off < 1024; off <<= 1){
    int v = (t + off < 1024) ? suf[t + off] : 0;
    __syncthreads();
    suf[t] += v;
    __syncthreads();
  }
  const int above = (t < 1023) ? suf[t + 1] : 0;
  if (above < KMASK && KMASK <= suf[t]){
    int cum = above;
    for (int bb = 15; bb >= 0; bb--){
      int c = local[bb];
      if (cum + c >= KMASK){ sh_B = base + bb; sh_kp = KMASK - cum; break; }
      cum += c;
    }
  }
  if (t == 0) cnt = 0;
  __syncthreads();
  const unsigned B = (unsigned)sh_B;
  const int kp = sh_kp;

  for (int i = t; i < PS; i += 1024){
    unsigned u = fkey(attn[i]);
    if ((u >> 18) == B){
      int p = atomicAdd(&cnt, 1);
      if (p < 4096){ ck[p] = u; ci[p] = i; }
    }
  }
  __syncthreads();
  int n = cnt; if (n > 4096) n = 4096;
  for (int p = t; p < n; p += 1024){
    const unsigned mk = ck[p]; const int mi = ci[p];
    int rank = 0;
    for (int j = 0; j < n; j++){
      const unsigned kj = ck[j];
      rank += (kj > mk) || (kj == mk && ci[j] < mi);
    }
    if (rank == kp - 1){ sh_C = mk; sh_thr = mi; }
  }
  __syncthreads();
  const unsigned C = sh_C;
  const int thr = sh_thr;

  const int i = b * 1024 + t;
  const unsigned u = fkey(attn[i]);
  const bool kept = (u < C) || (u == C && i > thr);
  const unsigned long long bal = __ballot(kept);
  const int lane = t & 63, w = t >> 6;
  if (lane == 0) wbase[w] = __popcll(bal);
  int cnt2 = 0;
  for (int j = t; j < b * 1024; j += 1024){
    const unsigned u2 = fkey(attn[j]);
    cnt2 += (u2 < C) || (u2 == C && j > thr);
  }
  suf[t] = cnt2; __syncthreads();
  for (int st = 512; st > 0; st >>= 1){ if (t < st) suf[t] += suf[t + st]; __syncthreads(); }
  if (t == 0){
    sh_base = suf[0];
    int run = 0;
    for (int j = 0; j < 16; j++){ int c = wbase[j]; wbase[j] = run; run += c; }
  }
  __syncthreads();
  if (kept){
    const int lr = __popcll(bal & ((1ull << lane) - 1ull));
    keep_ids[sh_base + wbase[w] + lr] = i;
  }
}

// ---------------------------------------------------------------------------
// Streaming gather: x[keep] f32 -> xbf bf16. 4096 blocks x 256 thr, 4 rows
// each (1 float4/thread/row). Pure-BW kernel (~100MB traffic).
// ---------------------------------------------------------------------------
__global__ __launch_bounds__(256) void k_gather(const float* __restrict__ x,
                                                const int* __restrict__ keep,
                                                u16* __restrict__ xbf){
  const int t = threadIdx.x;
  const int j0 = blockIdx.x * 4;
#pragma unroll
  for (int r = 0; r < 4; r++){
    const int j = j0 + r;
    const int id = keep[j];
    const float4 v = ((const float4*)(x + (size_t)id * DIN))[t];
    ushort4 pk;
    pk.x = f2bf_hw(v.x); pk.y = f2bf_hw(v.y);
    pk.z = f2bf_hw(v.z); pk.w = f2bf_hw(v.w);
    ((ushort4*)(xbf + (size_t)j * DIN))[t] = pk;
  }
}

// ---------------------------------------------------------------------------
// GEMM1: h = relu(xbf @ W_emb + b) -> bf16. Both A and B via global_load_lds
// (no VGPR round-trip). Triple-buffered, ONE raw s_barrier per iter, counted
// vmcnt(2) (2 K-steps in flight). Safety: buffer (k+2)%3 is overwritten only
// after barrier k, by which point every wave has finished MFMA(k-1) reads.
// Retire order: pairs issued A,B in k-order; vmcnt(2) retires exactly pair k.
// 512 thr, 8 waves (2x4), 128x128 tile, XCD swizzle. LDS 48KB.
// ---------------------------------------------------------------------------
__global__ __launch_bounds__(512) void k_gemm1(const u16* __restrict__ xbf,
                                               const u16* __restrict__ wet,
                                               const float* __restrict__ bemb,
                                               u16* __restrict__ hbf){
  __shared__ __align__(16) u16 As[3][128 * 32];
  __shared__ __align__(16) u16 Bs[3][128 * 32];
  const int t = threadIdx.x;
  const int wid = t >> 6, lane = t & 63;
  const int g = lane >> 4, li = lane & 15;
  const int m_ = blockIdx.x;
  const int by = (m_ & 7) + 8 * (m_ >> 5);
  const int bx = (m_ >> 3) & 3;
  const int brow = by * 128, bcol = bx * 128;
  const int wrow0 = (wid >> 2) * 64, wcol0 = (wid & 3) * 32;

  f32x4 acc[4][2];
  for (int mm = 0; mm < 4; mm++)
    for (int nn = 0; nn < 2; nn++)
      acc[mm][nn] = (f32x4){0.f, 0.f, 0.f, 0.f};

  // per-wave GLDS sources: 16 rows x 64B per K-step (1KB = 1 GLDS16)
  const int r4 = lane >> 2, c4 = lane & 3;
  const u16* gA = xbf + ((size_t)(brow + wid * 16 + r4) * DIN + c4 * 8);
  const u16* gB = wet + ((size_t)(bcol + wid * 16 + r4) * DIN + c4 * 8);

#define READ_MFMA(cur) { \
    short8 a_[4], b_[2]; \
    _Pragma("unroll") \
    for (int mm = 0; mm < 4; mm++) \
      a_[mm] = *(const short8*)&As[cur][(wrow0 + mm * 16 + li) * 32 + g * 8]; \
    _Pragma("unroll") \
    for (int nn = 0; nn < 2; nn++) \
      b_[nn] = *(const short8*)&Bs[cur][(wcol0 + nn * 16 + li) * 32 + g * 8]; \
    for (int mm = 0; mm < 4; mm++) \
      for (int nn = 0; nn < 2; nn++) \
        acc[mm][nn] = __builtin_amdgcn_mfma_f32_16x16x32_bf16(a_[mm], b_[nn], acc[mm][nn], 0, 0, 0); }

  // prologue: issue pairs 0 and 1
  GLDS16(gA,      &As[0][wid * 512]);
  GLDS16(gB,      &Bs[0][wid * 512]);
  MEMPIN();
  GLDS16(gA + 32, &As[1][wid * 512]);
  GLDS16(gB + 32, &Bs[1][wid * 512]);
  MEMPIN();

  // main loop k = 0..29: wait pair k, barrier, MFMA, issue pair k+2
#pragma unroll 3
  for (int k = 0; k < 30; k++){
    asm volatile("s_waitcnt vmcnt(2)" ::: "memory");   // pair k resident
    __builtin_amdgcn_s_barrier();                      // all waves' pair k in LDS
    READ_MFMA(k % 3);
    MEMPIN();
    GLDS16(gA + (k + 2) * 32, &As[(k + 2) % 3][wid * 512]);
    GLDS16(gB + (k + 2) * 32, &Bs[(k + 2) % 3][wid * 512]);
    MEMPIN();
  }
  // k = 30: wait pair 30 (leave pair 31 in flight)
  asm volatile("s_waitcnt vmcnt(2)" ::: "memory");
  __builtin_amdgcn_s_barrier();
  READ_MFMA(0);                                        // 30 % 3 = 0
  // k = 31
  asm volatile("s_waitcnt vmcnt(0)" ::: "memory");
  __builtin_amdgcn_s_barrier();
  READ_MFMA(1);                                        // 31 % 3 = 1
#undef READ_MFMA

  for (int nn = 0; nn < 2; nn++){
    const int col = bcol + wcol0 + nn * 16 + li;
    const float be = bemb[col];
    for (int mm = 0; mm < 4; mm++){
      const int row0 = brow + wrow0 + mm * 16 + g * 4;
      f32x4 v = acc[mm][nn];
      for (int r = 0; r < 4; r++){
        float val = v[r] + be;
        if (val < 0.f) val = 0.f;
        hbf[(size_t)(row0 + r) * DMID + col] = f2bf(val);
      }
    }
  }
}

// ---------------------------------------------------------------------------
// GEMM2 + gelu + W_a2 dot -> s; epilogue: per-block stats + flash-style local
// feat vec_b -> partial[b][512] (R17/R18-verified).
// ---------------------------------------------------------------------------
__global__ __launch_bounds__(256) void k_gemm2(const u16* __restrict__ hbf,
                                               const u16* __restrict__ wa1t,
                                               const float* __restrict__ ba1,
                                               const float* __restrict__ wa2,
                                               const float* __restrict__ ba2,
                                               float* __restrict__ s_out,
                                               float* __restrict__ smax,
                                               float* __restrict__ ssum,
                                               float* __restrict__ partial){
  __shared__ __align__(16) u16 As[64 * 32];
  __shared__ __align__(16) u16 Bs[128 * 32];
  __shared__ float p_lds[64];
  __shared__ float sh_m;
  const int t = threadIdx.x;
  const int wid = t >> 6, lane = t & 63;
  const int g = lane >> 4, li = lane & 15;
  const int brow = blockIdx.x * 64;
  const int wrow0 = (wid >> 1) * 32, wcol0 = (wid & 1) * 64;

  f32x4 acc[2][4];
  for (int m = 0; m < 2; m++)
    for (int n = 0; n < 4; n++)
      acc[m][n] = (f32x4){0.f, 0.f, 0.f, 0.f};

  const int r4 = lane >> 2, c4 = lane & 3;
  const u16* gA = hbf  + ((size_t)(brow + wid * 16 + r4) * DMID + c4 * 8);
  const u16* gB = wa1t + ((size_t)(wid * 32 + r4) * DMID + c4 * 8);
  u16* lA = As + wid * 512;
  u16* lB = Bs + wid * 1024;

  for (int k0 = 0; k0 < DMID; k0 += 32){
    GLDS16(gA + k0,             lA);
    GLDS16(gB + k0,             lB);
    GLDS16(gB + 16 * DMID + k0, lB + 512);
    __syncthreads();
    short8 a[2], b[4];
    for (int m = 0; m < 2; m++)
      a[m] = *(const short8*)&As[(wrow0 + m * 16 + li) * 32 + g * 8];
    for (int n = 0; n < 4; n++)
      b[n] = *(const short8*)&Bs[(wcol0 + n * 16 + li) * 32 + g * 8];
    for (int m = 0; m < 2; m++)
      for (int n = 0; n < 4; n++)
        acc[m][n] = __builtin_amdgcn_mfma_f32_16x16x32_bf16(a[m], b[n], acc[m][n], 0, 0, 0);
    __syncthreads();
  }

  float rsum[2][4] = {{0.f,0.f,0.f,0.f},{0.f,0.f,0.f,0.f}};
  for (int n = 0; n < 4; n++){
    const int col = wcol0 + n * 16 + li;
    const float b1 = ba1[col], w2 = wa2[col];
    for (int m = 0; m < 2; m++){
      f32x4 v = acc[m][n];
      for (int r = 0; r < 4; r++){
        float xv = v[r] + b1;
        float ge = 0.5f * xv * (1.0f + erff(xv * 0.70710678118654752f)); // exact gelu
        rsum[m][r] += ge * w2;
      }
    }
  }
  const float bb = ba2[0];
  for (int m = 0; m < 2; m++){
    for (int r = 0; r < 4; r++){
      float v = rsum[m][r];
      v += __shfl_xor(v, 1); v += __shfl_xor(v, 2);
      v += __shfl_xor(v, 4); v += __shfl_xor(v, 8);
      if (li == 0) s_out[brow + wrow0 + m * 16 + g * 4 + r] = v + bb;
    }
  }
  __syncthreads();   // s writes visible block-wide
  if (t < 64){
    const float sv = s_out[brow + t];
    float mx = sv;
    for (int off = 1; off < 64; off <<= 1) mx = fmaxf(mx, __shfl_xor(mx, off));
    float ez = expf(sv - mx);
    for (int off = 1; off < 64; off <<= 1) ez += __shfl_xor(ez, off);
    if (t == 0){ smax[blockIdx.x] = mx; ssum[blockIdx.x] = ez; sh_m = mx; }
  }
  __syncthreads();
  if (t < 64) p_lds[t] = expf(s_out[brow + t] - sh_m);
  __syncthreads();
  {
    const int d0 = t * 2;
    float v0 = 0.f, v1 = 0.f;
    for (int j = 0; j < 64; j++){
      const float pj = p_lds[j];
      const unsigned hv = *(const unsigned*)&hbf[(size_t)(brow + j) * DMID + d0];
      v0 += pj * bf2f((u16)(hv & 0xffffu));
      v1 += pj * bf2f((u16)(hv >> 16));
    }
    partial[(size_t)blockIdx.x * DMID + d0]     = v0;
    partial[(size_t)blockIdx.x * DMID + d0 + 1] = v1;
  }
}

// ---------------------------------------------------------------------------
// Final: online-softmax merge of 256 block partials + logits + soft-CE loss.
// One block x 512.
// ---------------------------------------------------------------------------
__global__ __launch_bounds__(512) void k_final(const float* __restrict__ partial,
                                               const float* __restrict__ smax,
                                               const float* __restrict__ ssum,
                                               const float* __restrict__ teach,
                                               const float* __restrict__ Wp,
                                               const float* __restrict__ bp,
                                               float* __restrict__ out){
  __shared__ float red[512];
  __shared__ float coef[256];
  const int t = threadIdx.x;

  red[t] = (t < 256) ? smax[t] : -INFINITY; __syncthreads();
  for (int st = 256; st > 0; st >>= 1){ if (t < st) red[t] = fmaxf(red[t], red[t + st]); __syncthreads(); }
  const float m_s = red[0]; __syncthreads();
  if (t < 256) coef[t] = expf(smax[t] - m_s);
  __syncthreads();
  red[t] = (t < 256) ? ssum[t] * coef[t] : 0.f; __syncthreads();
  for (int st = 256; st > 0; st >>= 1){ if (t < st) red[t] += red[t + st]; __syncthreads(); }
  const float invZ = 1.0f / red[0]; __syncthreads();

  float f = 0.f;
  for (int b = 0; b < 256; b++) f += partial[(size_t)b * DMID + t] * coef[b];
  f *= invZ;
  const float td = teach[t];

  red[t] = f; __syncthreads();
  for (int st = 256; st > 0; st >>= 1){ if (t < st) red[t] = fmaxf(red[t], red[t + st]); __syncthreads(); }
  const float mf = red[0]; __syncthreads();

  red[t] = td; __syncthreads();
  for (int st = 256; st > 0; st >>= 1){ if (t < st) red[t] = fmaxf(red[t], red[t + st]); __syncthreads(); }
  const float mt = red[0]; __syncthreads();

  red[t] = expf(f - mf); __syncthreads();
  for (int st = 256; st > 0; st >>= 1){ if (t < st) red[t] += red[t + st]; __syncthreads(); }
  const float Zf = red[0]; __syncthreads();

  const float pt = expf(td - mt);
  red[t] = pt; __syncthreads();
  for (int st = 256; st > 0; st >>= 1){ if (t < st) red[t] += red[t + st]; __syncthreads(); }
  const float Zt = red[0]; __syncthreads();

  red[t] = pt * f; __syncthreads();
  for (int st = 256; st > 0; st >>= 1){ if (t < st) red[t] += red[t + st]; __syncthreads(); }
  const float S1 = red[0]; __syncthreads();

  red[t] = f * Wp[t * 2 + 0]; __syncthreads();
  for (int st = 256; st > 0; st >>= 1){ if (t < st) red[t] += red[t + st]; __syncthreads(); }
  const float L0 = red[0]; __syncthreads();

  red[t] = f * Wp[t * 2 + 1]; __syncthreads();
  for (int st = 256; st > 0; st >>= 1){ if (t < st) red[t] += red[t + st]; __syncthreads(); }
  const float L1 = red[0];

  if (t == 0){
    out[0] = L0 + bp[0];
    out[1] = L1 + bp[1];
    out[2] = (mf + logf(Zf)) - S1 / Zt;
  }
}

// ---------------------------------------------------------------------------
// ws layout (bytes):
//   [0)        keep_ids int[16384] | [65536) s f32[16384]
//   [131072)   smax f32[256] | [132096) ssum f32[256]
//   [200704)   wet bf16[512][1024] | [1249280) wa1t bf16[128][512]
//   [1380352)  xbf bf16[16384][1024] = 33.5MB (gather -> gemm1);
//              partial f32[256][512] aliases xbf (disjoint in time)
//   [34934784) hbf bf16[16384][512]
// ---------------------------------------------------------------------------
extern "C" void kernel_launch(void* const* d_in, const int* in_sizes, int n_in,
                              void* d_out, int out_size, void* d_ws, size_t ws_size,
                              hipStream_t stream){
  const float* x     = (const float*)d_in[0];
  const float* attn  = (const float*)d_in[1];
  const float* teach = (const float*)d_in[2];
  const float* Wemb  = (const float*)d_in[3];
  const float* bemb  = (const float*)d_in[4];
  const float* Wa1   = (const float*)d_in[5];
  const float* ba1   = (const float*)d_in[6];
  const float* Wa2   = (const float*)d_in[7];
  const float* ba2   = (const float*)d_in[8];
  const float* Wp    = (const float*)d_in[9];
  const float* bp    = (const float*)d_in[10];
  float* out = (float*)d_out;

  char* ws = (char*)d_ws;
  int*   keep = (int*)(ws + 0);
  float* s    = (float*)(ws + 65536);
  float* smax = (float*)(ws + 131072);
  float* ssum = (float*)(ws + 132096);
  u16*   wet  = (u16*)(ws + 200704);
  u16*   wa1t = (u16*)(ws + 200704 + 1048576);
  u16*   xbf  = (u16*)(ws + 1380352);
  float* partial = (float*)xbf;       // aliases xbf, disjoint in time
  u16*   hbf  = (u16*)(ws + 34934784);

  k_head<<<dim3(176), dim3(1024), 0, stream>>>(attn, keep, Wemb, wet, Wa1, wa1t);
  k_gather<<<dim3(4096), dim3(256), 0, stream>>>(x, keep, xbf);
  k_gemm1<<<dim3(512), dim3(512), 0, stream>>>(xbf, wet, bemb, hbf);
  k_gemm2<<<dim3(LKEEP / 64), dim3(256), 0, stream>>>(hbf, wa1t, ba1, Wa2, ba2, s, smax, ssum, partial);
  k_final<<<dim3(1), dim3(512), 0, stream>>>(partial, smax, ssum, teach, Wp, bp, out);
}

// Round 24
// 107.568 us; speedup vs baseline: 1.0778x; 1.0778x over previous
//
#include <hip/hip_runtime.h>
#include <hip/hip_bf16.h>
#include <math.h>

// Problem constants
#define PS    32768
#define DIN   1024
#define DMID  512
#define DATT  128
#define KMASK 16384
#define LKEEP 16384

typedef unsigned short u16;
typedef __attribute__((ext_vector_type(8))) short short8;
typedef __attribute__((ext_vector_type(4))) float f32x4;

__device__ __forceinline__ u16 f2bf(float f){
  unsigned x = __float_as_uint(f);
  unsigned r = (x + 0x7fffu + ((x >> 16) & 1u)) >> 16;  // RNE
  return (u16)r;
}
__device__ __forceinline__ u16 f2bf_hw(float f){
  __hip_bfloat16 h = __float2bfloat16(f);    // RNE; pairs fuse to v_cvt_pk_bf16_f32
  return *reinterpret_cast<u16*>(&h);
}
__device__ __forceinline__ float bf2f(u16 u){
  return __uint_as_float(((unsigned)u) << 16);
}
// monotonic key: larger float -> larger unsigned
__device__ __forceinline__ unsigned fkey(float f){
  unsigned b = __float_as_uint(f);
  return (b & 0x80000000u) ? ~b : (b | 0x80000000u);
}

#define GLDS16(g,l) __builtin_amdgcn_global_load_lds( \
    (const __attribute__((address_space(1))) void*)(g), \
    (__attribute__((address_space(3))) void*)(l), 16, 0, 0)

#define MEMPIN() asm volatile("" ::: "memory")

// ---------------------------------------------------------------------------
// Head kernel (R21-proven): blocks 0..31 = selection; blocks 32..175 = prep.
// ---------------------------------------------------------------------------
__global__ __launch_bounds__(1024) void k_head(const float* __restrict__ attn,
                                               int* __restrict__ keep_ids,
                                               const float* __restrict__ Wemb,
                                               u16* __restrict__ wet,
                                               const float* __restrict__ Wa1,
                                               u16* __restrict__ wa1t){
  __shared__ int histL[16384];
  __shared__ int suf[1024];
  __shared__ unsigned ck[4096];
  __shared__ int ci[4096];
  __shared__ float tile[4][32][33];
  __shared__ int sh_B, sh_kp, cnt;
  __shared__ unsigned sh_C;
  __shared__ int sh_thr;
  __shared__ int wbase[16];
  __shared__ int sh_base;
  const int t = threadIdx.x, b = blockIdx.x;

  if (b >= 32){
    const int grp = t >> 8, ts = t & 255;
    const int ob = (b - 32) * 4 + grp;
    const int tx = ts & 31, ty = ts >> 5;
    if (ob < 512){
      const int c0 = (ob & 15) * 32, r0 = (ob >> 4) * 32;   // Wemb [1024][512]
      for (int i = 0; i < 32; i += 8)
        tile[grp][ty + i][tx] = Wemb[(size_t)(r0 + ty + i) * DMID + c0 + tx];
      __syncthreads();
      for (int i = 0; i < 32; i += 8)
        wet[(size_t)(c0 + ty + i) * DIN + r0 + tx] = f2bf(tile[grp][tx][ty + i]);
    } else {
      const int b2 = ob - 512;                               // Wa1 [512][128]
      const int c0 = (b2 & 3) * 32, r0 = (b2 >> 2) * 32;
      for (int i = 0; i < 32; i += 8)
        tile[grp][ty + i][tx] = Wa1[(size_t)(r0 + ty + i) * DATT + c0 + tx];
      __syncthreads();
      for (int i = 0; i < 32; i += 8)
        wa1t[(size_t)(c0 + ty + i) * DMID + r0 + tx] = f2bf(tile[grp][tx][ty + i]);
    }
    return;
  }

  // selection (R19-proven)
  for (int i = t; i < 16384; i += 1024) histL[i] = 0;
  __syncthreads();
  for (int i = t; i < PS; i += 1024)
    atomicAdd(&histL[fkey(attn[i]) >> 18], 1);
  __syncthreads();

  int local[16]; int s = 0;
  const int base = t * 16;
  for (int j = 0; j < 16; j++){ local[j] = histL[base + j]; s += local[j]; }
  suf[t] = s; __syncthreads();
  for (int off = 1; off < 1024; off <<= 1){
    int v = (t + off < 1024) ? suf[t + off] : 0;
    __syncthreads();
    suf[t] += v;
    __syncthreads();
  }
  const int above = (t < 1023) ? suf[t + 1] : 0;
  if (above < KMASK && KMASK <= suf[t]){
    int cum = above;
    for (int bb = 15; bb >= 0; bb--){
      int c = local[bb];
      if (cum + c >= KMASK){ sh_B = base + bb; sh_kp = KMASK - cum; break; }
      cum += c;
    }
  }
  if (t == 0) cnt = 0;
  __syncthreads();
  const unsigned B = (unsigned)sh_B;
  const int kp = sh_kp;

  for (int i = t; i < PS; i += 1024){
    unsigned u = fkey(attn[i]);
    if ((u >> 18) == B){
      int p = atomicAdd(&cnt, 1);
      if (p < 4096){ ck[p] = u; ci[p] = i; }
    }
  }
  __syncthreads();
  int n = cnt; if (n > 4096) n = 4096;
  for (int p = t; p < n; p += 1024){
    const unsigned mk = ck[p]; const int mi = ci[p];
    int rank = 0;
    for (int j = 0; j < n; j++){
      const unsigned kj = ck[j];
      rank += (kj > mk) || (kj == mk && ci[j] < mi);
    }
    if (rank == kp - 1){ sh_C = mk; sh_thr = mi; }
  }
  __syncthreads();
  const unsigned C = sh_C;
  const int thr = sh_thr;

  const int i = b * 1024 + t;
  const unsigned u = fkey(attn[i]);
  const bool kept = (u < C) || (u == C && i > thr);
  const unsigned long long bal = __ballot(kept);
  const int lane = t & 63, w = t >> 6;
  if (lane == 0) wbase[w] = __popcll(bal);
  int cnt2 = 0;
  for (int j = t; j < b * 1024; j += 1024){
    const unsigned u2 = fkey(attn[j]);
    cnt2 += (u2 < C) || (u2 == C && j > thr);
  }
  suf[t] = cnt2; __syncthreads();
  for (int st = 512; st > 0; st >>= 1){ if (t < st) suf[t] += suf[t + st]; __syncthreads(); }
  if (t == 0){
    sh_base = suf[0];
    int run = 0;
    for (int j = 0; j < 16; j++){ int c = wbase[j]; wbase[j] = run; run += c; }
  }
  __syncthreads();
  if (kept){
    const int lr = __popcll(bal & ((1ull << lane) - 1ull));
    keep_ids[sh_base + wbase[w] + lr] = i;
  }
}

// ---------------------------------------------------------------------------
// GEMM1 fused gather — T3/T4 pipelined K-loop (R22-proven, best measured):
// raw s_barrier + COUNTED vmcnt. Double-buffered As/Bs. Per iter k: issue
// B(k+1) GLDS + A(k+2) reg loads (B first -> B(k) oldest; vmcnt(5) retires
// exactly it); ds_read+MFMA on cur; cvt+write A(k+1)->As[nxt];
// lgkmcnt(0)+s_barrier — B(k+1), A(k+2) stay in flight ACROSS the barrier.
// Last two iterations peeled (vmcnt(3), vmcnt(0)). 512 thr, 8 waves, 128x128.
// ---------------------------------------------------------------------------
__global__ __launch_bounds__(512) void k_gemm1g(const float* __restrict__ xg,
                                                const int* __restrict__ keep,
                                                const u16* __restrict__ wet,
                                                const float* __restrict__ bemb,
                                                u16* __restrict__ hbf){
  __shared__ __align__(16) u16 As[2][128 * 32];
  __shared__ __align__(16) u16 Bs[2][128 * 32];
  const int t = threadIdx.x;
  const int wid = t >> 6, lane = t & 63;
  const int g = lane >> 4, li = lane & 15;
  const int m_ = blockIdx.x;
  const int by = (m_ & 7) + 8 * (m_ >> 5);
  const int bx = (m_ >> 3) & 3;
  const int brow = by * 128, bcol = bx * 128;
  const int wrow0 = (wid >> 2) * 64, wcol0 = (wid & 3) * 32;

  f32x4 acc[4][2];
  for (int mm = 0; mm < 4; mm++)
    for (int nn = 0; nn < 2; nn++)
      acc[mm][nn] = (f32x4){0.f, 0.f, 0.f, 0.f};

  const int rsub = t >> 2, q8 = (t & 3) * 8;
  const float* gA = xg + (size_t)keep[brow + rsub] * DIN + q8;
  const int r4 = lane >> 2, cB = lane & 3;
  const u16* gB = wet + ((size_t)(bcol + wid * 16 + r4) * DIN + cB * 8);

#define CVT_STORE(dstbuf, lo, hi) { \
    short8 pk_; \
    pk_[0] = (short)f2bf_hw((lo).x); pk_[1] = (short)f2bf_hw((lo).y); \
    pk_[2] = (short)f2bf_hw((lo).z); pk_[3] = (short)f2bf_hw((lo).w); \
    pk_[4] = (short)f2bf_hw((hi).x); pk_[5] = (short)f2bf_hw((hi).y); \
    pk_[6] = (short)f2bf_hw((hi).z); pk_[7] = (short)f2bf_hw((hi).w); \
    *(short8*)&As[dstbuf][rsub * 32 + q8] = pk_; }

#define READ_MFMA(cur) { \
    short8 a_[4], b_[2]; \
    _Pragma("unroll") \
    for (int mm = 0; mm < 4; mm++) \
      a_[mm] = *(const short8*)&As[cur][(wrow0 + mm * 16 + li) * 32 + g * 8]; \
    _Pragma("unroll") \
    for (int nn = 0; nn < 2; nn++) \
      b_[nn] = *(const short8*)&Bs[cur][(wcol0 + nn * 16 + li) * 32 + g * 8]; \
    for (int mm = 0; mm < 4; mm++) \
      for (int nn = 0; nn < 2; nn++) \
        acc[mm][nn] = __builtin_amdgcn_mfma_f32_16x16x32_bf16(a_[mm], b_[nn], acc[mm][nn], 0, 0, 0); }

  // ---- prologue: A(0), B(0), A(1); cvt A(0); drain B(0) once ----
  float4 a0lo = *(const float4*)(gA);
  float4 a0hi = *(const float4*)(gA + 4);
  MEMPIN();
  GLDS16(gB, &Bs[0][wid * 512]);
  MEMPIN();
  float4 avlo = *(const float4*)(gA + 32);
  float4 avhi = *(const float4*)(gA + 36);
  MEMPIN();
  CVT_STORE(0, a0lo, a0hi);                       // compiler waits A(0)
  asm volatile("s_waitcnt vmcnt(2) lgkmcnt(0)" ::: "memory");  // retire B(0); A(1)x2 in flight
  __builtin_amdgcn_s_barrier();

  // ---- main loop k = 0..29 ----
#pragma unroll 2
  for (int k = 0; k < 30; k++){
    const int cur = k & 1, nxt = cur ^ 1;
    GLDS16(gB + (k + 1) * 32, &Bs[nxt][wid * 512]);   // B(k+1)
    MEMPIN();
    float4 nvlo = *(const float4*)(gA + (k + 2) * 32); // A(k+2)
    float4 nvhi = *(const float4*)(gA + (k + 2) * 32 + 4);
    asm volatile("s_waitcnt vmcnt(5)" ::: "memory");   // retire B(k) exactly
    READ_MFMA(cur);
    MEMPIN();
    CVT_STORE(nxt, avlo, avhi);                        // A(k+1) (compiler waits)
    avlo = nvlo; avhi = nvhi;
    asm volatile("s_waitcnt lgkmcnt(0)" ::: "memory");
    __builtin_amdgcn_s_barrier();                      // B(k+1), A(k+2) stay in flight
  }
  // ---- k = 30 (no A(32); issue B(31)) ----
  {
    GLDS16(gB + 31 * 32, &Bs[1][wid * 512]);           // B(31) (nxt=1)
    asm volatile("s_waitcnt vmcnt(3)" ::: "memory");   // retire B(30)
    READ_MFMA(0);                                      // cur = 30&1 = 0
    MEMPIN();
    CVT_STORE(1, avlo, avhi);                          // A(31)
    asm volatile("s_waitcnt lgkmcnt(0)" ::: "memory");
    __builtin_amdgcn_s_barrier();
  }
  // ---- k = 31 ----
  {
    asm volatile("s_waitcnt vmcnt(0)" ::: "memory");   // B(31) done
    READ_MFMA(1);
  }
#undef CVT_STORE
#undef READ_MFMA

  for (int nn = 0; nn < 2; nn++){
    const int col = bcol + wcol0 + nn * 16 + li;
    const float be = bemb[col];
    for (int mm = 0; mm < 4; mm++){
      const int row0 = brow + wrow0 + mm * 16 + g * 4;
      f32x4 v = acc[mm][nn];
      for (int r = 0; r < 4; r++){
        float val = v[r] + be;
        if (val < 0.f) val = 0.f;
        hbf[(size_t)(row0 + r) * DMID + col] = f2bf(val);
      }
    }
  }
}

// ---------------------------------------------------------------------------
// GEMM2 + gelu + W_a2 dot -> s; epilogue: per-block stats + flash-style local
// feat vec_b -> partial[b][512] (R17/R18-verified).
// ---------------------------------------------------------------------------
__global__ __launch_bounds__(256) void k_gemm2(const u16* __restrict__ hbf,
                                               const u16* __restrict__ wa1t,
                                               const float* __restrict__ ba1,
                                               const float* __restrict__ wa2,
                                               const float* __restrict__ ba2,
                                               float* __restrict__ s_out,
                                               float* __restrict__ smax,
                                               float* __restrict__ ssum,
                                               float* __restrict__ partial){
  __shared__ __align__(16) u16 As[64 * 32];
  __shared__ __align__(16) u16 Bs[128 * 32];
  __shared__ float p_lds[64];
  __shared__ float sh_m;
  const int t = threadIdx.x;
  const int wid = t >> 6, lane = t & 63;
  const int g = lane >> 4, li = lane & 15;
  const int brow = blockIdx.x * 64;
  const int wrow0 = (wid >> 1) * 32, wcol0 = (wid & 1) * 64;

  f32x4 acc[2][4];
  for (int m = 0; m < 2; m++)
    for (int n = 0; n < 4; n++)
      acc[m][n] = (f32x4){0.f, 0.f, 0.f, 0.f};

  const int r4 = lane >> 2, c4 = lane & 3;
  const u16* gA = hbf  + ((size_t)(brow + wid * 16 + r4) * DMID + c4 * 8);
  const u16* gB = wa1t + ((size_t)(wid * 32 + r4) * DMID + c4 * 8);
  u16* lA = As + wid * 512;
  u16* lB = Bs + wid * 1024;

  for (int k0 = 0; k0 < DMID; k0 += 32){
    GLDS16(gA + k0,             lA);
    GLDS16(gB + k0,             lB);
    GLDS16(gB + 16 * DMID + k0, lB + 512);
    __syncthreads();
    short8 a[2], b[4];
    for (int m = 0; m < 2; m++)
      a[m] = *(const short8*)&As[(wrow0 + m * 16 + li) * 32 + g * 8];
    for (int n = 0; n < 4; n++)
      b[n] = *(const short8*)&Bs[(wcol0 + n * 16 + li) * 32 + g * 8];
    for (int m = 0; m < 2; m++)
      for (int n = 0; n < 4; n++)
        acc[m][n] = __builtin_amdgcn_mfma_f32_16x16x32_bf16(a[m], b[n], acc[m][n], 0, 0, 0);
    __syncthreads();
  }

  float rsum[2][4] = {{0.f,0.f,0.f,0.f},{0.f,0.f,0.f,0.f}};
  for (int n = 0; n < 4; n++){
    const int col = wcol0 + n * 16 + li;
    const float b1 = ba1[col], w2 = wa2[col];
    for (int m = 0; m < 2; m++){
      f32x4 v = acc[m][n];
      for (int r = 0; r < 4; r++){
        float xv = v[r] + b1;
        float ge = 0.5f * xv * (1.0f + erff(xv * 0.70710678118654752f)); // exact gelu
        rsum[m][r] += ge * w2;
      }
    }
  }
  const float bb = ba2[0];
  for (int m = 0; m < 2; m++){
    for (int r = 0; r < 4; r++){
      float v = rsum[m][r];
      v += __shfl_xor(v, 1); v += __shfl_xor(v, 2);
      v += __shfl_xor(v, 4); v += __shfl_xor(v, 8);
      if (li == 0) s_out[brow + wrow0 + m * 16 + g * 4 + r] = v + bb;
    }
  }
  __syncthreads();   // s writes visible block-wide
  if (t < 64){
    const float sv = s_out[brow + t];
    float mx = sv;
    for (int off = 1; off < 64; off <<= 1) mx = fmaxf(mx, __shfl_xor(mx, off));
    float ez = expf(sv - mx);
    for (int off = 1; off < 64; off <<= 1) ez += __shfl_xor(ez, off);
    if (t == 0){ smax[blockIdx.x] = mx; ssum[blockIdx.x] = ez; sh_m = mx; }
  }
  __syncthreads();
  if (t < 64) p_lds[t] = expf(s_out[brow + t] - sh_m);
  __syncthreads();
  {
    const int d0 = t * 2;
    float v0 = 0.f, v1 = 0.f;
    for (int j = 0; j < 64; j++){
      const float pj = p_lds[j];
      const unsigned hv = *(const unsigned*)&hbf[(size_t)(brow + j) * DMID + d0];
      v0 += pj * bf2f((u16)(hv & 0xffffu));
      v1 += pj * bf2f((u16)(hv >> 16));
    }
    partial[(size_t)blockIdx.x * DMID + d0]     = v0;
    partial[(size_t)blockIdx.x * DMID + d0 + 1] = v1;
  }
}

// ---------------------------------------------------------------------------
// Final: online-softmax merge of 256 block partials + logits + soft-CE loss.
// One block x 512.
// ---------------------------------------------------------------------------
__global__ __launch_bounds__(512) void k_final(const float* __restrict__ partial,
                                               const float* __restrict__ smax,
                                               const float* __restrict__ ssum,
                                               const float* __restrict__ teach,
                                               const float* __restrict__ Wp,
                                               const float* __restrict__ bp,
                                               float* __restrict__ out){
  __shared__ float red[512];
  __shared__ float coef[256];
  const int t = threadIdx.x;

  red[t] = (t < 256) ? smax[t] : -INFINITY; __syncthreads();
  for (int st = 256; st > 0; st >>= 1){ if (t < st) red[t] = fmaxf(red[t], red[t + st]); __syncthreads(); }
  const float m_s = red[0]; __syncthreads();
  if (t < 256) coef[t] = expf(smax[t] - m_s);
  __syncthreads();
  red[t] = (t < 256) ? ssum[t] * coef[t] : 0.f; __syncthreads();
  for (int st = 256; st > 0; st >>= 1){ if (t < st) red[t] += red[t + st]; __syncthreads(); }
  const float invZ = 1.0f / red[0]; __syncthreads();

  float f = 0.f;
  for (int b = 0; b < 256; b++) f += partial[(size_t)b * DMID + t] * coef[b];
  f *= invZ;
  const float td = teach[t];

  red[t] = f; __syncthreads();
  for (int st = 256; st > 0; st >>= 1){ if (t < st) red[t] = fmaxf(red[t], red[t + st]); __syncthreads(); }
  const float mf = red[0]; __syncthreads();

  red[t] = td; __syncthreads();
  for (int st = 256; st > 0; st >>= 1){ if (t < st) red[t] = fmaxf(red[t], red[t + st]); __syncthreads(); }
  const float mt = red[0]; __syncthreads();

  red[t] = expf(f - mf); __syncthreads();
  for (int st = 256; st > 0; st >>= 1){ if (t < st) red[t] += red[t + st]; __syncthreads(); }
  const float Zf = red[0]; __syncthreads();

  const float pt = expf(td - mt);
  red[t] = pt; __syncthreads();
  for (int st = 256; st > 0; st >>= 1){ if (t < st) red[t] += red[t + st]; __syncthreads(); }
  const float Zt = red[0]; __syncthreads();

  red[t] = pt * f; __syncthreads();
  for (int st = 256; st > 0; st >>= 1){ if (t < st) red[t] += red[t + st]; __syncthreads(); }
  const float S1 = red[0]; __syncthreads();

  red[t] = f * Wp[t * 2 + 0]; __syncthreads();
  for (int st = 256; st > 0; st >>= 1){ if (t < st) red[t] += red[t + st]; __syncthreads(); }
  const float L0 = red[0]; __syncthreads();

  red[t] = f * Wp[t * 2 + 1]; __syncthreads();
  for (int st = 256; st > 0; st >>= 1){ if (t < st) red[t] += red[t + st]; __syncthreads(); }
  const float L1 = red[0];

  if (t == 0){
    out[0] = L0 + bp[0];
    out[1] = L1 + bp[1];
    out[2] = (mf + logf(Zf)) - S1 / Zt;
  }
}

// ---------------------------------------------------------------------------
// ws layout (bytes):
//   [0)        keep_ids int[16384] | [65536) s f32[16384]
//   [131072)   smax f32[256] | [132096) ssum f32[256]
//   [200704)   wet bf16[512][1024] | [1249280) wa1t bf16[128][512]
//   [1380352)  partial f32[256][512] = 512KB
//   [34934784) hbf bf16[16384][512]
// ---------------------------------------------------------------------------
extern "C" void kernel_launch(void* const* d_in, const int* in_sizes, int n_in,
                              void* d_out, int out_size, void* d_ws, size_t ws_size,
                              hipStream_t stream){
  const float* x     = (const float*)d_in[0];
  const float* attn  = (const float*)d_in[1];
  const float* teach = (const float*)d_in[2];
  const float* Wemb  = (const float*)d_in[3];
  const float* bemb  = (const float*)d_in[4];
  const float* Wa1   = (const float*)d_in[5];
  const float* ba1   = (const float*)d_in[6];
  const float* Wa2   = (const float*)d_in[7];
  const float* ba2   = (const float*)d_in[8];
  const float* Wp    = (const float*)d_in[9];
  const float* bp    = (const float*)d_in[10];
  float* out = (float*)d_out;

  char* ws = (char*)d_ws;
  int*   keep = (int*)(ws + 0);
  float* s    = (float*)(ws + 65536);
  float* smax = (float*)(ws + 131072);
  float* ssum = (float*)(ws + 132096);
  u16*   wet  = (u16*)(ws + 200704);
  u16*   wa1t = (u16*)(ws + 200704 + 1048576);
  float* partial = (float*)(ws + 200704 + 1048576 + 131072);
  u16*   hbf  = (u16*)(ws + 200704 + 1048576 + 131072 + 33554432);

  k_head<<<dim3(176), dim3(1024), 0, stream>>>(attn, keep, Wemb, wet, Wa1, wa1t);
  k_gemm1g<<<dim3(512), dim3(512), 0, stream>>>(x, keep, wet, bemb, hbf);
  k_gemm2<<<dim3(LKEEP / 64), dim3(256), 0, stream>>>(hbf, wa1t, ba1, Wa2, ba2, s, smax, ssum, partial);
  k_final<<<dim3(1), dim3(512), 0, stream>>>(partial, smax, ssum, teach, Wp, bp, out);
}